// Round 1
// baseline (959.732 us; speedup 1.0000x reference)
//
#include <hip/hip_runtime.h>
#include <hip/hip_bf16.h>

#define N_USERS   100000
#define N_ITEMS   50000
#define N_TOTAL   150000
#define DIM       64
#define NNZ       4000000
#define BATCH     8192
#define SCAN_BLOCKS ((N_TOTAL + 1023) / 1024)   // 147

// ---------------------------------------------------------------------------
// Init: x_a = concat(user_emb, item_emb); zero fill (hist counters) + partials
// ---------------------------------------------------------------------------
__global__ void k_init(const float* __restrict__ ue, const float* __restrict__ ie,
                       float* __restrict__ x, int* __restrict__ fill,
                       int* __restrict__ partials) {
    int tid = blockIdx.x * blockDim.x + threadIdx.x;
    const int tot = N_TOTAL * DIM;
    if (tid < tot) {
        float v = (tid < N_USERS * DIM) ? ue[tid] : ie[tid - N_USERS * DIM];
        x[tid] = v;
    }
    if (tid < N_TOTAL) fill[tid] = 0;
    if (tid < 1024) partials[tid] = 0;
}

// ---------------------------------------------------------------------------
// Histogram of row indices
// ---------------------------------------------------------------------------
__global__ void k_hist(const int* __restrict__ rows, int* __restrict__ fill) {
    int e = blockIdx.x * blockDim.x + threadIdx.x;
    if (e < NNZ) atomicAdd(&fill[rows[e]], 1);
}

// ---------------------------------------------------------------------------
// Per-1024-chunk sums of counts -> partials
// ---------------------------------------------------------------------------
__global__ void k_blocksum(const int* __restrict__ counts, int* __restrict__ partials) {
    int b = blockIdx.x, t = threadIdx.x;
    int base = b * 1024;
    int s = 0;
    for (int k = t; k < 1024; k += 256) {
        int i = base + k;
        if (i < N_TOTAL) s += counts[i];
    }
    for (int off = 32; off; off >>= 1) s += __shfl_down(s, off, 64);
    __shared__ int sm[4];
    if ((t & 63) == 0) sm[t >> 6] = s;
    __syncthreads();
    if (t == 0) partials[b] = sm[0] + sm[1] + sm[2] + sm[3];
}

// ---------------------------------------------------------------------------
// Serial exclusive scan of partials (147 elements - trivial)
// ---------------------------------------------------------------------------
__global__ void k_scanpart(int* __restrict__ partials, int* __restrict__ row_ptr) {
    if (blockIdx.x == 0 && threadIdx.x == 0) {
        int acc = 0;
        for (int i = 0; i < SCAN_BLOCKS; ++i) {
            int v = partials[i];
            partials[i] = acc;
            acc += v;
        }
        row_ptr[N_TOTAL] = acc;   // == NNZ
    }
}

// ---------------------------------------------------------------------------
// Per-block exclusive scan; writes row_ptr and resets fill = row_ptr for scatter
// ---------------------------------------------------------------------------
__global__ void k_blockscan(int* __restrict__ fill, int* __restrict__ row_ptr,
                            const int* __restrict__ partials) {
    __shared__ int tmp[1024];
    int b = blockIdx.x, t = threadIdx.x;
    int i = b * 1024 + t;
    int v = (i < N_TOTAL) ? fill[i] : 0;
    tmp[t] = v;
    __syncthreads();
    for (int off = 1; off < 1024; off <<= 1) {
        int a = (t >= off) ? tmp[t - off] : 0;
        __syncthreads();
        if (t >= off) tmp[t] += a;
        __syncthreads();
    }
    int excl = tmp[t] - v;
    if (i < N_TOTAL) {
        int val = partials[b] + excl;
        row_ptr[i] = val;
        fill[i] = val;
    }
}

// ---------------------------------------------------------------------------
// Scatter (col, val) pairs into CSR order
// ---------------------------------------------------------------------------
__global__ void k_scatter(const int* __restrict__ rows, const int* __restrict__ cols,
                          const float* __restrict__ vals, int* __restrict__ fill,
                          uint2* __restrict__ pairs) {
    int e = blockIdx.x * blockDim.x + threadIdx.x;
    if (e < NNZ) {
        int r = rows[e];
        int pos = atomicAdd(&fill[r], 1);
        pairs[pos] = make_uint2((unsigned)cols[e], __float_as_uint(vals[e]));
    }
}

// ---------------------------------------------------------------------------
// SpMM: one wave per row, lane = dim. x_out[r] = sum_j val_j * x_in[col_j]
// ---------------------------------------------------------------------------
__global__ void k_spmm(const int* __restrict__ row_ptr, const uint2* __restrict__ pairs,
                       const float* __restrict__ x_in, float* __restrict__ x_out) {
    int gw   = (blockIdx.x * blockDim.x + threadIdx.x) >> 6;
    int lane = threadIdx.x & 63;
    if (gw >= N_TOTAL) return;
    int s = row_ptr[gw], e = row_ptr[gw + 1];
    float a0 = 0.f, a1 = 0.f, a2 = 0.f, a3 = 0.f;
    int j = s;
    for (; j + 4 <= e; j += 4) {
        uint2 p0 = pairs[j];
        uint2 p1 = pairs[j + 1];
        uint2 p2 = pairs[j + 2];
        uint2 p3 = pairs[j + 3];
        a0 += __uint_as_float(p0.y) * x_in[(int)p0.x * DIM + lane];
        a1 += __uint_as_float(p1.y) * x_in[(int)p1.x * DIM + lane];
        a2 += __uint_as_float(p2.y) * x_in[(int)p2.x * DIM + lane];
        a3 += __uint_as_float(p3.y) * x_in[(int)p3.x * DIM + lane];
    }
    for (; j < e; ++j) {
        uint2 p = pairs[j];
        a0 += __uint_as_float(p.y) * x_in[(int)p.x * DIM + lane];
    }
    x_out[gw * DIM + lane] = (a0 + a1) + (a2 + a3);
}

// ---------------------------------------------------------------------------
// Accumulate the 3*BATCH needed rows of the current layer output into sacc
// ---------------------------------------------------------------------------
__global__ void k_gacc(const int* __restrict__ users, const int* __restrict__ pos,
                       const int* __restrict__ neg, const float* __restrict__ x,
                       float* __restrict__ sacc, int init) {
    int tid = blockIdx.x * blockDim.x + threadIdx.x;
    int j = tid >> 6, lane = tid & 63;
    if (j >= 3 * BATCH) return;
    int row;
    if (j < BATCH)            row = users[j];
    else if (j < 2 * BATCH)   row = N_USERS + pos[j - BATCH];
    else                      row = N_USERS + neg[j - 2 * BATCH];
    float v = x[row * DIM + lane];
    if (init) sacc[tid] = v;
    else      sacc[tid] += v;
}

// ---------------------------------------------------------------------------
// Final: scores (dot products over light_out rows) + raw layer-0 embeddings
// ---------------------------------------------------------------------------
__global__ void k_final(const float* __restrict__ sacc, const float* __restrict__ ue,
                        const float* __restrict__ ie, const int* __restrict__ users,
                        const int* __restrict__ pos, const int* __restrict__ neg,
                        float* __restrict__ out) {
    int tid = blockIdx.x * blockDim.x + threadIdx.x;
    int b = tid >> 6, lane = tid & 63;
    if (b >= BATCH) return;
    float ul = sacc[b * DIM + lane] * 0.25f;
    float pl = sacc[(BATCH + b) * DIM + lane] * 0.25f;
    float nl = sacc[(2 * BATCH + b) * DIM + lane] * 0.25f;
    float ps = ul * pl;
    float ns = ul * nl;
    for (int m = 1; m < 64; m <<= 1) {
        ps += __shfl_xor(ps, m, 64);
        ns += __shfl_xor(ns, m, 64);
    }
    if (lane == 0) {
        out[b] = ps;
        out[BATCH + b] = ns;
    }
    int u = users[b], p = pos[b], ng = neg[b];
    float* o = out + 2 * BATCH;
    o[b * DIM + lane]                  = ue[u * DIM + lane];
    o[BATCH * DIM + b * DIM + lane]    = ie[p * DIM + lane];
    o[2 * BATCH * DIM + b * DIM + lane] = ie[ng * DIM + lane];
}

// ---------------------------------------------------------------------------
extern "C" void kernel_launch(void* const* d_in, const int* in_sizes, int n_in,
                              void* d_out, int out_size, void* d_ws, size_t ws_size,
                              hipStream_t stream) {
    const float* user_emb = (const float*)d_in[0];
    const float* item_emb = (const float*)d_in[1];
    const float* adj_vals = (const float*)d_in[2];
    const int*   adj_rows = (const int*)d_in[3];
    const int*   adj_cols = (const int*)d_in[4];
    const int*   users    = (const int*)d_in[5];
    const int*   pos      = (const int*)d_in[6];
    const int*   neg      = (const int*)d_in[7];
    float* out = (float*)d_out;

    char* ws = (char*)d_ws;
    const size_t SZ_X = (size_t)N_TOTAL * DIM * sizeof(float);   // 38,400,000
    float* x_a     = (float*)(ws);
    float* x_b     = (float*)(ws + SZ_X);
    uint2* pairs   = (uint2*)(ws + 2 * SZ_X);
    int*   row_ptr = (int*)(ws + 2 * SZ_X + (size_t)NNZ * 8);
    int*   fill    = row_ptr + (N_TOTAL + 64);
    int*   partials= fill + (N_TOTAL + 64);
    float* sacc    = (float*)(partials + 1024);

    const int TPB = 256;

    // 1) init x_a + zero counters
    k_init<<<(N_TOTAL * DIM + TPB - 1) / TPB, TPB, 0, stream>>>(user_emb, item_emb, x_a, fill, partials);
    // 2) histogram
    k_hist<<<NNZ / TPB, TPB, 0, stream>>>(adj_rows, fill);
    // 3) two-level exclusive scan -> row_ptr, fill = row_ptr
    k_blocksum<<<SCAN_BLOCKS, TPB, 0, stream>>>(fill, partials);
    k_scanpart<<<1, 64, 0, stream>>>(partials, row_ptr);
    k_blockscan<<<SCAN_BLOCKS, 1024, 0, stream>>>(fill, row_ptr, partials);
    // 4) scatter pairs into CSR order
    k_scatter<<<NNZ / TPB, TPB, 0, stream>>>(adj_rows, adj_cols, adj_vals, fill, pairs);

    // 5) small_acc = layer-0 rows
    k_gacc<<<(3 * BATCH * DIM) / TPB, TPB, 0, stream>>>(users, pos, neg, x_a, sacc, 1);

    // 6) three propagation layers, ping-pong x_a/x_b
    const int SPMM_BLOCKS = (N_TOTAL * DIM + TPB - 1) / TPB;   // one wave per row
    k_spmm<<<SPMM_BLOCKS, TPB, 0, stream>>>(row_ptr, pairs, x_a, x_b);
    k_gacc<<<(3 * BATCH * DIM) / TPB, TPB, 0, stream>>>(users, pos, neg, x_b, sacc, 0);
    k_spmm<<<SPMM_BLOCKS, TPB, 0, stream>>>(row_ptr, pairs, x_b, x_a);
    k_gacc<<<(3 * BATCH * DIM) / TPB, TPB, 0, stream>>>(users, pos, neg, x_a, sacc, 0);
    k_spmm<<<SPMM_BLOCKS, TPB, 0, stream>>>(row_ptr, pairs, x_a, x_b);
    k_gacc<<<(3 * BATCH * DIM) / TPB, TPB, 0, stream>>>(users, pos, neg, x_b, sacc, 0);

    // 7) final outputs
    k_final<<<(BATCH * DIM) / TPB, TPB, 0, stream>>>(sacc, user_emb, item_emb, users, pos, neg, out);
}

// Round 2
// 583.046 us; speedup vs baseline: 1.6461x; 1.6461x over previous
//
#include <hip/hip_runtime.h>
#include <hip/hip_bf16.h>

#define N_USERS   100000
#define N_ITEMS   50000
#define N_TOTAL   150000
#define DIM       64
#define NNZ       4000000
#define BATCH     8192

#define NB        587                      // ceil(150000 / 256) buckets of 256 rows
#define PB        512                      // pass A/B blocks
#define CHUNK     ((NNZ + PB - 1) / PB)    // 7813 edges per block

// ---------------------------------------------------------------------------
// Init: x_a = concat(user_emb, item_emb); zero bucket totals
// ---------------------------------------------------------------------------
__global__ void k_init(const float* __restrict__ ue, const float* __restrict__ ie,
                       float* __restrict__ x, int* __restrict__ btotal) {
    int tid = blockIdx.x * blockDim.x + threadIdx.x;
    const int tot = N_TOTAL * DIM;
    if (tid < tot) {
        float v = (tid < N_USERS * DIM) ? ue[tid] : ie[tid - N_USERS * DIM];
        x[tid] = v;
    }
    if (tid < NB) btotal[tid] = 0;
}

// ---------------------------------------------------------------------------
// Pass A: per-block LDS bucket histogram; reserve per-(block,bucket) sub-range
// ---------------------------------------------------------------------------
__global__ void k_bcount(const int* __restrict__ rows, int* __restrict__ btotal,
                         int* __restrict__ myBase) {
    __shared__ int h[NB];
    for (int i = threadIdx.x; i < NB; i += 256) h[i] = 0;
    __syncthreads();
    int s = blockIdx.x * CHUNK;
    int e = s + CHUNK; if (e > NNZ) e = NNZ;
    for (int j = s + threadIdx.x; j < e; j += 256)
        atomicAdd(&h[rows[j] >> 8], 1);
    __syncthreads();
    for (int i = threadIdx.x; i < NB; i += 256) {
        int c = h[i];
        myBase[blockIdx.x * NB + i] = c ? atomicAdd(&btotal[i], c) : 0;
    }
}

// ---------------------------------------------------------------------------
// Serial exclusive scan of bucket totals (587 values - trivial)
// ---------------------------------------------------------------------------
__global__ void k_bscan(const int* __restrict__ btotal, int* __restrict__ bbase,
                        int* __restrict__ row_ptr) {
    if (threadIdx.x == 0) {
        int acc = 0;
        for (int i = 0; i < NB; ++i) {
            bbase[i] = acc;
            acc += btotal[i];
        }
        bbase[NB] = acc;            // == NNZ
        row_ptr[N_TOTAL] = acc;
    }
}

// ---------------------------------------------------------------------------
// Pass B: append edges into per-(block,bucket) reserved sub-ranges.
// Packed: (rowlow << 18) | col  (col < 2^18, rowlow < 2^8)
// ---------------------------------------------------------------------------
__global__ void k_bucket(const int* __restrict__ rows, const int* __restrict__ cols,
                         const float* __restrict__ vals, const int* __restrict__ bbase,
                         const int* __restrict__ myBase, uint2* __restrict__ bucketed) {
    __shared__ int cnt[NB];
    for (int i = threadIdx.x; i < NB; i += 256)
        cnt[i] = bbase[i] + myBase[blockIdx.x * NB + i];
    __syncthreads();
    int s = blockIdx.x * CHUNK;
    int e = s + CHUNK; if (e > NNZ) e = NNZ;
    for (int j = s + threadIdx.x; j < e; j += 256) {
        int r = rows[j];
        int bkt = r >> 8;
        int p = atomicAdd(&cnt[bkt], 1);
        bucketed[p] = make_uint2(((unsigned)(r & 255) << 18) | (unsigned)cols[j],
                                 __float_as_uint(vals[j]));
    }
}

// ---------------------------------------------------------------------------
// Pass C: one block per bucket. LDS row-hist -> block scan -> row_ptr,
// then L2-local scatter into final CSR (col, val) pairs.
// ---------------------------------------------------------------------------
__global__ void k_csr(const uint2* __restrict__ bucketed, const int* __restrict__ bbase,
                      uint2* __restrict__ pairs, int* __restrict__ row_ptr) {
    __shared__ int rc[256];
    __shared__ int sc[256];
    __shared__ int fillc[256];
    int b = blockIdx.x, t = threadIdx.x;
    int s = bbase[b], e = bbase[b + 1];
    rc[t] = 0;
    __syncthreads();
    for (int j = s + t; j < e; j += 256)
        atomicAdd(&rc[bucketed[j].x >> 18], 1);
    __syncthreads();
    // Hillis-Steele inclusive scan of rc -> sc
    sc[t] = rc[t];
    __syncthreads();
    for (int off = 1; off < 256; off <<= 1) {
        int v = (t >= off) ? sc[t - off] : 0;
        __syncthreads();
        sc[t] += v;
        __syncthreads();
    }
    int excl = sc[t] - rc[t];
    int base = s + excl;
    fillc[t] = base;
    int row = b * 256 + t;
    if (row < N_TOTAL) row_ptr[row] = base;
    __syncthreads();
    for (int j = s + t; j < e; j += 256) {
        uint2 pr = bucketed[j];
        int pos = atomicAdd(&fillc[pr.x >> 18], 1);
        pairs[pos] = make_uint2(pr.x & 0x3FFFFu, pr.y);
    }
}

// ---------------------------------------------------------------------------
// SpMM: one wave per row, lane = dim. x_out[r] = sum_j val_j * x_in[col_j]
// ---------------------------------------------------------------------------
__global__ void k_spmm(const int* __restrict__ row_ptr, const uint2* __restrict__ pairs,
                       const float* __restrict__ x_in, float* __restrict__ x_out) {
    int gw   = (blockIdx.x * blockDim.x + threadIdx.x) >> 6;
    int lane = threadIdx.x & 63;
    if (gw >= N_TOTAL) return;
    int s = row_ptr[gw], e = row_ptr[gw + 1];
    float a0 = 0.f, a1 = 0.f, a2 = 0.f, a3 = 0.f;
    int j = s;
    for (; j + 4 <= e; j += 4) {
        uint2 p0 = pairs[j];
        uint2 p1 = pairs[j + 1];
        uint2 p2 = pairs[j + 2];
        uint2 p3 = pairs[j + 3];
        a0 += __uint_as_float(p0.y) * x_in[(int)p0.x * DIM + lane];
        a1 += __uint_as_float(p1.y) * x_in[(int)p1.x * DIM + lane];
        a2 += __uint_as_float(p2.y) * x_in[(int)p2.x * DIM + lane];
        a3 += __uint_as_float(p3.y) * x_in[(int)p3.x * DIM + lane];
    }
    for (; j < e; ++j) {
        uint2 p = pairs[j];
        a0 += __uint_as_float(p.y) * x_in[(int)p.x * DIM + lane];
    }
    x_out[gw * DIM + lane] = (a0 + a1) + (a2 + a3);
}

// ---------------------------------------------------------------------------
// Accumulate the 3*BATCH needed rows of the current layer output into sacc
// ---------------------------------------------------------------------------
__global__ void k_gacc(const int* __restrict__ users, const int* __restrict__ pos,
                       const int* __restrict__ neg, const float* __restrict__ x,
                       float* __restrict__ sacc, int init) {
    int tid = blockIdx.x * blockDim.x + threadIdx.x;
    int j = tid >> 6, lane = tid & 63;
    if (j >= 3 * BATCH) return;
    int row;
    if (j < BATCH)            row = users[j];
    else if (j < 2 * BATCH)   row = N_USERS + pos[j - BATCH];
    else                      row = N_USERS + neg[j - 2 * BATCH];
    float v = x[row * DIM + lane];
    if (init) sacc[tid] = v;
    else      sacc[tid] += v;
}

// ---------------------------------------------------------------------------
// Final: scores (dot products over light_out rows) + raw layer-0 embeddings
// ---------------------------------------------------------------------------
__global__ void k_final(const float* __restrict__ sacc, const float* __restrict__ ue,
                        const float* __restrict__ ie, const int* __restrict__ users,
                        const int* __restrict__ pos, const int* __restrict__ neg,
                        float* __restrict__ out) {
    int tid = blockIdx.x * blockDim.x + threadIdx.x;
    int b = tid >> 6, lane = tid & 63;
    if (b >= BATCH) return;
    float ul = sacc[b * DIM + lane] * 0.25f;
    float pl = sacc[(BATCH + b) * DIM + lane] * 0.25f;
    float nl = sacc[(2 * BATCH + b) * DIM + lane] * 0.25f;
    float ps = ul * pl;
    float ns = ul * nl;
    for (int m = 1; m < 64; m <<= 1) {
        ps += __shfl_xor(ps, m, 64);
        ns += __shfl_xor(ns, m, 64);
    }
    if (lane == 0) {
        out[b] = ps;
        out[BATCH + b] = ns;
    }
    int u = users[b], p = pos[b], ng = neg[b];
    float* o = out + 2 * BATCH;
    o[b * DIM + lane]                   = ue[u * DIM + lane];
    o[BATCH * DIM + b * DIM + lane]     = ie[p * DIM + lane];
    o[2 * BATCH * DIM + b * DIM + lane] = ie[ng * DIM + lane];
}

// ---------------------------------------------------------------------------
extern "C" void kernel_launch(void* const* d_in, const int* in_sizes, int n_in,
                              void* d_out, int out_size, void* d_ws, size_t ws_size,
                              hipStream_t stream) {
    const float* user_emb = (const float*)d_in[0];
    const float* item_emb = (const float*)d_in[1];
    const float* adj_vals = (const float*)d_in[2];
    const int*   adj_rows = (const int*)d_in[3];
    const int*   adj_cols = (const int*)d_in[4];
    const int*   users    = (const int*)d_in[5];
    const int*   pos      = (const int*)d_in[6];
    const int*   neg      = (const int*)d_in[7];
    float* out = (float*)d_out;

    char* ws = (char*)d_ws;
    const size_t SZ_X = (size_t)N_TOTAL * DIM * sizeof(float);   // 38,400,000 B
    float* x_a     = (float*)(ws);
    float* x_b     = (float*)(ws + SZ_X);
    uint2* bucketed= (uint2*)x_b;                 // alias: dead before x_b is written
    uint2* pairs   = (uint2*)(ws + 2 * SZ_X);
    char*  p3      = ws + 2 * SZ_X + (size_t)NNZ * 8;
    int*   row_ptr = (int*)p3;                    // N_TOTAL + 1 (+pad)
    int*   btotal  = row_ptr + (N_TOTAL + 64);
    int*   bbase   = btotal + (NB + 64);          // NB + 1
    int*   myBase  = bbase + (NB + 64);           // PB * NB
    float* sacc    = (float*)(myBase + PB * NB + 64);

    const int TPB = 256;

    // 1) init x_a + zero bucket totals
    k_init<<<(N_TOTAL * DIM + TPB - 1) / TPB, TPB, 0, stream>>>(user_emb, item_emb, x_a, btotal);
    // 2) CSR build: count -> scan -> bucket -> local scatter
    k_bcount<<<PB, TPB, 0, stream>>>(adj_rows, btotal, myBase);
    k_bscan<<<1, 64, 0, stream>>>(btotal, bbase, row_ptr);
    k_bucket<<<PB, TPB, 0, stream>>>(adj_rows, adj_cols, adj_vals, bbase, myBase, bucketed);
    k_csr<<<NB, TPB, 0, stream>>>(bucketed, bbase, pairs, row_ptr);

    // 3) small_acc = layer-0 rows
    k_gacc<<<(3 * BATCH * DIM) / TPB, TPB, 0, stream>>>(users, pos, neg, x_a, sacc, 1);

    // 4) three propagation layers, ping-pong x_a/x_b
    const int SPMM_BLOCKS = (N_TOTAL * DIM + TPB - 1) / TPB;   // one wave per row
    k_spmm<<<SPMM_BLOCKS, TPB, 0, stream>>>(row_ptr, pairs, x_a, x_b);
    k_gacc<<<(3 * BATCH * DIM) / TPB, TPB, 0, stream>>>(users, pos, neg, x_b, sacc, 0);
    k_spmm<<<SPMM_BLOCKS, TPB, 0, stream>>>(row_ptr, pairs, x_b, x_a);
    k_gacc<<<(3 * BATCH * DIM) / TPB, TPB, 0, stream>>>(users, pos, neg, x_a, sacc, 0);
    k_spmm<<<SPMM_BLOCKS, TPB, 0, stream>>>(row_ptr, pairs, x_a, x_b);
    k_gacc<<<(3 * BATCH * DIM) / TPB, TPB, 0, stream>>>(users, pos, neg, x_b, sacc, 0);

    // 5) final outputs
    k_final<<<(BATCH * DIM) / TPB, TPB, 0, stream>>>(sacc, user_emb, item_emb, users, pos, neg, out);
}

// Round 3
// 556.129 us; speedup vs baseline: 1.7257x; 1.0484x over previous
//
#include <hip/hip_runtime.h>
#include <hip/hip_bf16.h>

#define N_USERS   100000
#define N_ITEMS   50000
#define N_TOTAL   150000
#define DIM       64
#define NNZ       4000000
#define BATCH     8192

#define NB        587                      // ceil(150000 / 256) buckets of 256 rows
#define PB        512                      // pass A/B blocks
#define CHUNK     ((NNZ + PB - 1) / PB)    // 7813 edges per block

// bf16 helpers (manual RNE round; unpack via shift)
__device__ __forceinline__ unsigned f2bf_bits(float f) {
    unsigned u = __float_as_uint(f);
    return (u + 0x7FFFu + ((u >> 16) & 1u)) >> 16;
}
__device__ __forceinline__ float bf2f_lo(unsigned w) { return __uint_as_float(w << 16); }
__device__ __forceinline__ float bf2f_hi(unsigned w) { return __uint_as_float(w & 0xFFFF0000u); }

// ---------------------------------------------------------------------------
// Init: x_a = bf16(concat(user_emb, item_emb)); zero bucket totals
// ---------------------------------------------------------------------------
__global__ void k_init(const float* __restrict__ ue, const float* __restrict__ ie,
                       unsigned short* __restrict__ x, int* __restrict__ btotal) {
    int tid = blockIdx.x * blockDim.x + threadIdx.x;       // one per 4 elems
    const int tot4 = N_TOTAL * DIM / 4;
    if (tid < tot4) {
        const int uelems = N_USERS * DIM;
        int base = tid * 4;
        float4 v = (base < uelems) ? ((const float4*)ue)[tid]
                                   : ((const float4*)ie)[(base - uelems) / 4];
        ushort2 lo = make_ushort2((unsigned short)f2bf_bits(v.x), (unsigned short)f2bf_bits(v.y));
        ushort2 hi = make_ushort2((unsigned short)f2bf_bits(v.z), (unsigned short)f2bf_bits(v.w));
        ((ushort2*)x)[tid * 2]     = lo;
        ((ushort2*)x)[tid * 2 + 1] = hi;
    }
    if (tid < NB) btotal[tid] = 0;
}

// ---------------------------------------------------------------------------
// Pass A: per-block LDS bucket histogram; reserve per-(block,bucket) sub-range
// ---------------------------------------------------------------------------
__global__ void k_bcount(const int* __restrict__ rows, int* __restrict__ btotal,
                         int* __restrict__ myBase) {
    __shared__ int h[NB];
    for (int i = threadIdx.x; i < NB; i += 256) h[i] = 0;
    __syncthreads();
    int s = blockIdx.x * CHUNK;
    int e = s + CHUNK; if (e > NNZ) e = NNZ;
    for (int j = s + threadIdx.x; j < e; j += 256)
        atomicAdd(&h[rows[j] >> 8], 1);
    __syncthreads();
    for (int i = threadIdx.x; i < NB; i += 256) {
        int c = h[i];
        myBase[blockIdx.x * NB + i] = c ? atomicAdd(&btotal[i], c) : 0;
    }
}

// ---------------------------------------------------------------------------
// Serial exclusive scan of bucket totals (587 values - trivial)
// ---------------------------------------------------------------------------
__global__ void k_bscan(const int* __restrict__ btotal, int* __restrict__ bbase,
                        int* __restrict__ row_ptr) {
    if (threadIdx.x == 0) {
        int acc = 0;
        for (int i = 0; i < NB; ++i) {
            bbase[i] = acc;
            acc += btotal[i];
        }
        bbase[NB] = acc;            // == NNZ
        row_ptr[N_TOTAL] = acc;
    }
}

// ---------------------------------------------------------------------------
// Pass B: append edges into per-(block,bucket) reserved sub-ranges.
// Packed: (rowlow << 18) | col  (col < 2^18, rowlow < 2^8)
// ---------------------------------------------------------------------------
__global__ void k_bucket(const int* __restrict__ rows, const int* __restrict__ cols,
                         const float* __restrict__ vals, const int* __restrict__ bbase,
                         const int* __restrict__ myBase, uint2* __restrict__ bucketed) {
    __shared__ int cnt[NB];
    for (int i = threadIdx.x; i < NB; i += 256)
        cnt[i] = bbase[i] + myBase[blockIdx.x * NB + i];
    __syncthreads();
    int s = blockIdx.x * CHUNK;
    int e = s + CHUNK; if (e > NNZ) e = NNZ;
    for (int j = s + threadIdx.x; j < e; j += 256) {
        int r = rows[j];
        int bkt = r >> 8;
        int p = atomicAdd(&cnt[bkt], 1);
        bucketed[p] = make_uint2(((unsigned)(r & 255) << 18) | (unsigned)cols[j],
                                 __float_as_uint(vals[j]));
    }
}

// ---------------------------------------------------------------------------
// Pass C: one block per bucket. LDS row-hist -> block scan -> row_ptr,
// then L2-local scatter into final CSR (col, val) pairs.
// ---------------------------------------------------------------------------
__global__ void k_csr(const uint2* __restrict__ bucketed, const int* __restrict__ bbase,
                      uint2* __restrict__ pairs, int* __restrict__ row_ptr) {
    __shared__ int rc[256];
    __shared__ int sc[256];
    __shared__ int fillc[256];
    int b = blockIdx.x, t = threadIdx.x;
    int s = bbase[b], e = bbase[b + 1];
    rc[t] = 0;
    __syncthreads();
    for (int j = s + t; j < e; j += 256)
        atomicAdd(&rc[bucketed[j].x >> 18], 1);
    __syncthreads();
    sc[t] = rc[t];
    __syncthreads();
    for (int off = 1; off < 256; off <<= 1) {
        int v = (t >= off) ? sc[t - off] : 0;
        __syncthreads();
        sc[t] += v;
        __syncthreads();
    }
    int excl = sc[t] - rc[t];
    int base = s + excl;
    fillc[t] = base;
    int row = b * 256 + t;
    if (row < N_TOTAL) row_ptr[row] = base;
    __syncthreads();
    for (int j = s + t; j < e; j += 256) {
        uint2 pr = bucketed[j];
        int pos = atomicAdd(&fillc[pr.x >> 18], 1);
        pairs[pos] = make_uint2(pr.x & 0x3FFFFu, pr.y);
    }
}

// ---------------------------------------------------------------------------
// SpMM (bf16 x): one wave per row; half-wave per nnz, lane holds bfloat162.
// ---------------------------------------------------------------------------
__global__ void k_spmm(const int* __restrict__ row_ptr, const uint2* __restrict__ pairs,
                       const unsigned short* __restrict__ x_in,
                       unsigned short* __restrict__ x_out) {
    int gw   = (blockIdx.x * blockDim.x + threadIdx.x) >> 6;
    int lane = threadIdx.x & 63;
    if (gw >= N_TOTAL) return;
    int s = row_ptr[gw], e = row_ptr[gw + 1];
    int half = lane >> 5;          // which nnz of the pair
    int d2   = lane & 31;          // dim pair: dims 2*d2, 2*d2+1
    float a0 = 0.f, a1 = 0.f;
    int j = s;
    for (; j + 2 <= e; j += 2) {
        uint2 p = pairs[j + half];
        unsigned xu = *(const unsigned*)(x_in + (int)p.x * DIM + d2 * 2);
        float v = __uint_as_float(p.y);
        a0 += v * bf2f_lo(xu);
        a1 += v * bf2f_hi(xu);
    }
    if (j < e && half == 0) {
        uint2 p = pairs[j];
        unsigned xu = *(const unsigned*)(x_in + (int)p.x * DIM + d2 * 2);
        float v = __uint_as_float(p.y);
        a0 += v * bf2f_lo(xu);
        a1 += v * bf2f_hi(xu);
    }
    a0 += __shfl_xor(a0, 32, 64);
    a1 += __shfl_xor(a1, 32, 64);
    if (half == 0) {
        unsigned w = f2bf_bits(a0) | (f2bf_bits(a1) << 16);
        *(unsigned*)(x_out + gw * DIM + d2 * 2) = w;
    }
}

// ---------------------------------------------------------------------------
// Last layer: SpMM for sampled rows only, accumulate fp32 into sacc.
// ---------------------------------------------------------------------------
__global__ void k_spmm_rows(const int* __restrict__ row_ptr, const uint2* __restrict__ pairs,
                            const unsigned short* __restrict__ x_in,
                            const int* __restrict__ users, const int* __restrict__ pos,
                            const int* __restrict__ neg, float* __restrict__ sacc) {
    int w    = (blockIdx.x * blockDim.x + threadIdx.x) >> 6;
    int lane = threadIdx.x & 63;
    if (w >= 3 * BATCH) return;
    int row;
    if (w < BATCH)          row = users[w];
    else if (w < 2 * BATCH) row = N_USERS + pos[w - BATCH];
    else                    row = N_USERS + neg[w - 2 * BATCH];
    int s = row_ptr[row], e = row_ptr[row + 1];
    int half = lane >> 5;
    int d2   = lane & 31;
    float a0 = 0.f, a1 = 0.f;
    int j = s;
    for (; j + 2 <= e; j += 2) {
        uint2 p = pairs[j + half];
        unsigned xu = *(const unsigned*)(x_in + (int)p.x * DIM + d2 * 2);
        float v = __uint_as_float(p.y);
        a0 += v * bf2f_lo(xu);
        a1 += v * bf2f_hi(xu);
    }
    if (j < e && half == 0) {
        uint2 p = pairs[j];
        unsigned xu = *(const unsigned*)(x_in + (int)p.x * DIM + d2 * 2);
        float v = __uint_as_float(p.y);
        a0 += v * bf2f_lo(xu);
        a1 += v * bf2f_hi(xu);
    }
    a0 += __shfl_xor(a0, 32, 64);
    a1 += __shfl_xor(a1, 32, 64);
    if (half == 0) {
        float2* sp = (float2*)(sacc + w * DIM);
        float2 cur = sp[d2];
        cur.x += a0; cur.y += a1;
        sp[d2] = cur;
    }
}

// ---------------------------------------------------------------------------
// sacc init from the ORIGINAL fp32 embeddings (layer-0 term, exact)
// ---------------------------------------------------------------------------
__global__ void k_gacc_init(const int* __restrict__ users, const int* __restrict__ pos,
                            const int* __restrict__ neg, const float* __restrict__ ue,
                            const float* __restrict__ ie, float* __restrict__ sacc) {
    int tid = blockIdx.x * blockDim.x + threadIdx.x;
    int j = tid >> 6, lane = tid & 63;
    if (j >= 3 * BATCH) return;
    float v;
    if (j < BATCH)            v = ue[users[j] * DIM + lane];
    else if (j < 2 * BATCH)   v = ie[pos[j - BATCH] * DIM + lane];
    else                      v = ie[neg[j - 2 * BATCH] * DIM + lane];
    sacc[tid] = v;
}

// ---------------------------------------------------------------------------
// Accumulate sampled rows of a bf16 layer output into sacc
// ---------------------------------------------------------------------------
__global__ void k_gacc_add(const int* __restrict__ users, const int* __restrict__ pos,
                           const int* __restrict__ neg,
                           const unsigned short* __restrict__ x, float* __restrict__ sacc) {
    int tid = blockIdx.x * blockDim.x + threadIdx.x;
    int j = tid >> 6, lane = tid & 63;
    if (j >= 3 * BATCH) return;
    int row;
    if (j < BATCH)            row = users[j];
    else if (j < 2 * BATCH)   row = N_USERS + pos[j - BATCH];
    else                      row = N_USERS + neg[j - 2 * BATCH];
    unsigned short u = x[row * DIM + lane];
    sacc[tid] += __uint_as_float((unsigned)u << 16);
}

// ---------------------------------------------------------------------------
// Final: scores + raw layer-0 embeddings
// ---------------------------------------------------------------------------
__global__ void k_final(const float* __restrict__ sacc, const float* __restrict__ ue,
                        const float* __restrict__ ie, const int* __restrict__ users,
                        const int* __restrict__ pos, const int* __restrict__ neg,
                        float* __restrict__ out) {
    int tid = blockIdx.x * blockDim.x + threadIdx.x;
    int b = tid >> 6, lane = tid & 63;
    if (b >= BATCH) return;
    float ul = sacc[b * DIM + lane] * 0.25f;
    float pl = sacc[(BATCH + b) * DIM + lane] * 0.25f;
    float nl = sacc[(2 * BATCH + b) * DIM + lane] * 0.25f;
    float ps = ul * pl;
    float ns = ul * nl;
    for (int m = 1; m < 64; m <<= 1) {
        ps += __shfl_xor(ps, m, 64);
        ns += __shfl_xor(ns, m, 64);
    }
    if (lane == 0) {
        out[b] = ps;
        out[BATCH + b] = ns;
    }
    int u = users[b], p = pos[b], ng = neg[b];
    float* o = out + 2 * BATCH;
    o[b * DIM + lane]                   = ue[u * DIM + lane];
    o[BATCH * DIM + b * DIM + lane]     = ie[p * DIM + lane];
    o[2 * BATCH * DIM + b * DIM + lane] = ie[ng * DIM + lane];
}

// ---------------------------------------------------------------------------
extern "C" void kernel_launch(void* const* d_in, const int* in_sizes, int n_in,
                              void* d_out, int out_size, void* d_ws, size_t ws_size,
                              hipStream_t stream) {
    const float* user_emb = (const float*)d_in[0];
    const float* item_emb = (const float*)d_in[1];
    const float* adj_vals = (const float*)d_in[2];
    const int*   adj_rows = (const int*)d_in[3];
    const int*   adj_cols = (const int*)d_in[4];
    const int*   users    = (const int*)d_in[5];
    const int*   pos      = (const int*)d_in[6];
    const int*   neg      = (const int*)d_in[7];
    float* out = (float*)d_out;

    char* ws = (char*)d_ws;
    const size_t SZ_X = (size_t)N_TOTAL * DIM * 2;               // 19.2 MB (bf16)
    unsigned short* x_a = (unsigned short*)(ws);
    unsigned short* x_b = (unsigned short*)(ws + SZ_X);
    uint2* pairs    = (uint2*)(ws + 2 * SZ_X);
    uint2* bucketed = (uint2*)(ws + 2 * SZ_X + (size_t)NNZ * 8);
    char*  p3       = ws + 2 * SZ_X + 2 * (size_t)NNZ * 8;
    int*   row_ptr  = (int*)p3;                    // N_TOTAL + 1 (+pad)
    int*   btotal   = row_ptr + (N_TOTAL + 64);
    int*   bbase    = btotal + (NB + 64);          // NB + 1
    int*   myBase   = bbase + (NB + 64);           // PB * NB
    float* sacc     = (float*)(myBase + PB * NB + 64);

    const int TPB = 256;

    // 1) init x_a (bf16) + zero bucket totals
    k_init<<<(N_TOTAL * DIM / 4 + TPB - 1) / TPB, TPB, 0, stream>>>(user_emb, item_emb, x_a, btotal);
    // 2) CSR build: count -> scan -> bucket -> local scatter
    k_bcount<<<PB, TPB, 0, stream>>>(adj_rows, btotal, myBase);
    k_bscan<<<1, 64, 0, stream>>>(btotal, bbase, row_ptr);
    k_bucket<<<PB, TPB, 0, stream>>>(adj_rows, adj_cols, adj_vals, bbase, myBase, bucketed);
    k_csr<<<NB, TPB, 0, stream>>>(bucketed, bbase, pairs, row_ptr);

    // 3) sacc = layer-0 rows (exact fp32 from inputs)
    k_gacc_init<<<(3 * BATCH * DIM) / TPB, TPB, 0, stream>>>(users, pos, neg, user_emb, item_emb, sacc);

    // 4) layers 1,2 full; layer 3 sampled-rows only (fused accumulate)
    const int SPMM_BLOCKS = (N_TOTAL * 64 + TPB - 1) / TPB;
    k_spmm<<<SPMM_BLOCKS, TPB, 0, stream>>>(row_ptr, pairs, x_a, x_b);
    k_gacc_add<<<(3 * BATCH * DIM) / TPB, TPB, 0, stream>>>(users, pos, neg, x_b, sacc);
    k_spmm<<<SPMM_BLOCKS, TPB, 0, stream>>>(row_ptr, pairs, x_b, x_a);
    k_gacc_add<<<(3 * BATCH * DIM) / TPB, TPB, 0, stream>>>(users, pos, neg, x_a, sacc);
    k_spmm_rows<<<(3 * BATCH * 64) / TPB, TPB, 0, stream>>>(row_ptr, pairs, x_a, users, pos, neg, sacc);

    // 5) final outputs
    k_final<<<(BATCH * DIM) / TPB, TPB, 0, stream>>>(sacc, user_emb, item_emb, users, pos, neg, out);
}